// Round 6
// baseline (6203.752 us; speedup 1.0000x reference)
//
#include <hip/hip_runtime.h>
#include <math.h>

#define AM_PLAIN 0
#define AM_ENC   1
#define CM_PLAIN 0

typedef short bf16x8 __attribute__((ext_vector_type(8)));
typedef float f32x4 __attribute__((ext_vector_type(4)));

__device__ __forceinline__ float sigf(float x) { return 1.0f / (1.0f + expf(-x)); }

__device__ __forceinline__ unsigned short bf_rne(float f) {
  unsigned u = __float_as_uint(f);
  u += 0x7FFFu + ((u >> 16) & 1u);
  return (unsigned short)(u >> 16);
}
__device__ __forceinline__ float bf_f(unsigned short h) {
  return __uint_as_float(((unsigned)h) << 16);
}

// ---------------- fp32 VALU GEMM (kept for encoder input projection) ----------------
template<int AMODE, int BTWO, int CMODE, int CDIR>
__global__ __launch_bounds__(256)
void gemm_k(const float* __restrict__ Ap, int lda,
            const float* __restrict__ emb,
            const int* __restrict__ xidx,
            const float* __restrict__ hbuf,
            const unsigned long long* __restrict__ cand_in, int nblk_cand, int step,
            const float* __restrict__ B0, const float* __restrict__ B1, int ldb,
            const float* __restrict__ bias,
            float* __restrict__ Cp, int ldc, long long zstride, int kper,
            unsigned long long* __restrict__ cand_out,
            float* __restrict__ dout, int tcol)
{
  __shared__ float As[32][68];
  __shared__ float Bs[32][68];
  __shared__ int ys[(AMODE == AM_PLAIN) ? 1 : 64];

  const int tid = threadIdx.x;
  const int tx = tid & 15, my = tid >> 4;
  const int n0 = tx * 4, m0 = my * 4;
  const int nbase = blockIdx.x * 64, mbase = blockIdx.y * 64;
  const int bz = blockIdx.z;

  if (AMODE == AM_ENC) {
    if (tid < 64) ys[tid] = xidx[tid * 64 + blockIdx.y];
  }
  if (AMODE != AM_PLAIN) __syncthreads();

  float acc[4][4];
#pragma unroll
  for (int i = 0; i < 4; ++i)
#pragma unroll
    for (int j = 0; j < 4; ++j) acc[i][j] = 0.0f;

  const int kbeg = bz * kper;
  const int lrow = tid >> 3, lk = (tid & 7) * 4;

  for (int kc = 0; kc < kper; kc += 32) {
    const int kg = kbeg + kc;
#pragma unroll
    for (int rr = 0; rr < 64; rr += 32) {
      const int row = lrow + rr;
      const float* ap;
      if (AMODE == AM_PLAIN) {
        ap = Ap + (size_t)(mbase + row) * lda + kg + lk;
      } else {
        ap = emb + (size_t)ys[row] * 512 + kg + lk;
      }
      const float4 v = *(const float4*)ap;
      As[lk + 0][row] = v.x; As[lk + 1][row] = v.y;
      As[lk + 2][row] = v.z; As[lk + 3][row] = v.w;

      const int n = nbase + row;
      const float* bp = B0 + (size_t)n * ldb + kg + lk;
      const float4 w = *(const float4*)bp;
      Bs[lk + 0][row] = w.x; Bs[lk + 1][row] = w.y;
      Bs[lk + 2][row] = w.z; Bs[lk + 3][row] = w.w;
    }
    __syncthreads();
#pragma unroll
    for (int k = 0; k < 32; ++k) {
      const float4 a = *(const float4*)&As[k][m0];
      const float4 b = *(const float4*)&Bs[k][n0];
      acc[0][0] += a.x * b.x; acc[0][1] += a.x * b.y; acc[0][2] += a.x * b.z; acc[0][3] += a.x * b.w;
      acc[1][0] += a.y * b.x; acc[1][1] += a.y * b.y; acc[1][2] += a.y * b.z; acc[1][3] += a.y * b.w;
      acc[2][0] += a.z * b.x; acc[2][1] += a.z * b.y; acc[2][2] += a.z * b.z; acc[2][3] += a.z * b.w;
      acc[3][0] += a.w * b.x; acc[3][1] += a.w * b.y; acc[3][2] += a.w * b.z; acc[3][3] += a.w * b.w;
    }
    __syncthreads();
  }

#pragma unroll
  for (int i = 0; i < 4; ++i) {
    const int m = mbase + m0 + i;
#pragma unroll
    for (int j = 0; j < 4; ++j) {
      const int n = nbase + n0 + j;
      float v = acc[i][j];
      if (bias) v += bias[n];
      Cp[bz * zstride + (size_t)m * ldc + n] = v;
    }
  }
}

// ---------------- fused encoder: whole 64-step bidirectional recurrence, 1 kernel -------
// 2 blocks (one per direction) x 512 thr (8 waves). h kept in LDS as bf16 hi/lo MFMA
// fragments (64 KB); c in VGPRs; Whh pre-converted fragments (K=256, KC=8, 64 ntiles).
// Wave w owns j-tiles {w, w+8} (16 cols each) for ALL 4 gates -> register-local LSTM
// pointwise (thread holds gi,gf,gg,go for its (b,j) set). Per step: MFMA phase reads
// hfr; barrier; pointwise; scatter new h to hfr; barrier.
__global__ __launch_bounds__(512)
void enc_fused(const float* __restrict__ xwf, const float* __restrict__ xwb,
               const short* __restrict__ whhfF, const short* __restrict__ whhfB,
               float* __restrict__ hfinal, float* __restrict__ cfinal)
{
  __shared__ short hfr[32768];   // [(mt*8+kc)*2 + hl][512]  = 64 KB

  const int d = blockIdx.x;
  const float* xw = d ? xwb : xwf;
  const short* wf = d ? whhfB : whhfF;
  const int tid = threadIdx.x;
  const int lane = tid & 63, wv = tid >> 6;     // 8 waves
  const int lrow = lane & 15, lq = lane >> 4;

  // zero h fragments (h0 = 0)
  for (int i = tid; i < 16384; i += 512) ((int*)hfr)[i] = 0;
  __syncthreads();

  float c[2][16];
#pragma unroll
  for (int jtl = 0; jtl < 2; ++jtl)
#pragma unroll
    for (int el = 0; el < 16; ++el) c[jtl][el] = 0.f;

  for (int s = 0; s < 64; ++s) {
    const int t = d ? (63 - s) : s;
    float hnew[2][16];

#pragma unroll
    for (int jtl = 0; jtl < 2; ++jtl) {
      const int jt = wv + jtl * 8;
      f32x4 acc[4][4];   // [gate][mt]
      // init accumulators with x-projection (bias already included)
#pragma unroll
      for (int g = 0; g < 4; ++g)
#pragma unroll
        for (int mt = 0; mt < 4; ++mt)
#pragma unroll
          for (int r = 0; r < 4; ++r) {
            const int b = mt * 16 + lq * 4 + r;
            acc[g][mt][r] = xw[((size_t)(t * 64 + b)) * 1024 + g * 256 + jt * 16 + lrow];
          }
#pragma unroll
      for (int kc = 0; kc < 8; ++kc) {
        bf16x8 ah[4], al[4];
#pragma unroll
        for (int mt = 0; mt < 4; ++mt) {
          const short* ab = hfr + ((mt * 8 + kc) * 2) * 512 + lane * 8;
          ah[mt] = *(const bf16x8*)ab;
          al[mt] = *(const bf16x8*)(ab + 512);
        }
#pragma unroll
        for (int g = 0; g < 4; ++g) {
          const short* wb = wf + ((size_t)((g * 16 + jt) * 8 + kc)) * 1024 + lane * 8;
          const bf16x8 bhi = *(const bf16x8*)wb;
          const bf16x8 blo = *(const bf16x8*)(wb + 512);
#pragma unroll
          for (int mt = 0; mt < 4; ++mt) {
            acc[g][mt] = __builtin_amdgcn_mfma_f32_16x16x32_bf16(ah[mt], bhi, acc[g][mt], 0, 0, 0);
            acc[g][mt] = __builtin_amdgcn_mfma_f32_16x16x32_bf16(al[mt], bhi, acc[g][mt], 0, 0, 0);
            acc[g][mt] = __builtin_amdgcn_mfma_f32_16x16x32_bf16(ah[mt], blo, acc[g][mt], 0, 0, 0);
          }
        }
      }
      // pointwise LSTM update (register-local: all 4 gates at same (b,j))
#pragma unroll
      for (int el = 0; el < 16; ++el) {
        const int mt = el >> 2, r = el & 3;
        const float gi = acc[0][mt][r];
        const float gf = acc[1][mt][r];
        const float gg = acc[2][mt][r];
        const float go = acc[3][mt][r];
        const float cn = sigf(gf) * c[jtl][el] + sigf(gi) * tanhf(gg);
        c[jtl][el] = cn;
        hnew[jtl][el] = sigf(go) * tanhf(cn);
      }
    }

    __syncthreads();   // all hfr reads (MFMA phase) complete before overwrite
#pragma unroll
    for (int jtl = 0; jtl < 2; ++jtl) {
      const int jt = wv + jtl * 8;
#pragma unroll
      for (int el = 0; el < 16; ++el) {
        const int mt = el >> 2, r = el & 3;
        const int b = mt * 16 + lq * 4 + r;
        const int j = jt * 16 + lrow;
        const float hn = hnew[jtl][el];
        const unsigned short hh = bf_rne(hn);
        const unsigned short ll = bf_rne(hn - bf_f(hh));
        const int base = ((mt * 8 + (j >> 5)) * 2) * 512 + (((j >> 3) & 3) * 16 + (b & 15)) * 8 + (j & 7);
        hfr[base] = (short)hh;
        hfr[base + 512] = (short)ll;
        if (s == 63) {
          const size_t off = (size_t)b * 512 + d * 256 + j;
          hfinal[off] = hn;
          cfinal[off] = c[jtl][el];
        }
      }
    }
    __syncthreads();
  }
}

// ---------------- weight -> MFMA-fragment conversion (hi/lo bf16 split) ----------------
// frag[((nt*KC + kc)*2 + hl)*512 + lane*8 + e] holds W[n][k] with
// n = nt*16 + (lane&15), k = kc*32 + (lane>>4)*8 + e.  Rows split at k=split (p0|p1).
__global__ __launch_bounds__(256)
void wconv(const float* __restrict__ p0, const float* __restrict__ p1,
           int ld, int split, int KC, short* __restrict__ frag, int total)
{
  const int i = blockIdx.x * 256 + threadIdx.x;
  if (i >= total) return;
  const int lane = i & 63;
  const int ck = i >> 6;                 // nt*KC + kc
  const int kc = ck % KC;
  const int nt = ck / KC;
  const int n = nt * 16 + (lane & 15);
  const int k0 = kc * 32 + (lane >> 4) * 8;
  const float* src = (k0 < split) ? (p0 + (size_t)n * ld + k0)
                                  : (p1 + (size_t)n * ld + (k0 - split));
  const float4 v0 = *(const float4*)src;
  const float4 v1 = *(const float4*)(src + 4);
  const float x[8] = {v0.x, v0.y, v0.z, v0.w, v1.x, v1.y, v1.z, v1.w};
  bf16x8 vh, vl;
#pragma unroll
  for (int e = 0; e < 8; ++e) {
    const unsigned short h = bf_rne(x[e]);
    vh[e] = (short)h;
    vl[e] = (short)bf_rne(x[e] - bf_f(h));
  }
  const size_t base = (size_t)ck * 1024 + lane * 8;
  *(bf16x8*)(frag + base) = vh;
  *(bf16x8*)(frag + base + 512) = vl;
}

// h fp32 [64][512] -> fragment hi/lo (KC=16): frag[((mt*16+kc)*2+hl)*512 + lane*8 + e]
__global__ __launch_bounds__(256)
void h2frag(const float* __restrict__ h, short* __restrict__ frag)
{
  const int i = blockIdx.x * 256 + threadIdx.x;  // 4096 total
  const int lane = i & 63;
  const int ck = i >> 6;                          // mt*16 + kc
  const int b = (ck >> 4) * 16 + (lane & 15);
  const int k0 = (ck & 15) * 32 + (lane >> 4) * 8;
  const float* src = h + (size_t)b * 512 + k0;
  const float4 v0 = *(const float4*)src;
  const float4 v1 = *(const float4*)(src + 4);
  const float x[8] = {v0.x, v0.y, v0.z, v0.w, v1.x, v1.y, v1.z, v1.w};
  bf16x8 vh, vl;
#pragma unroll
  for (int e = 0; e < 8; ++e) {
    const unsigned short hh = bf_rne(x[e]);
    vh[e] = (short)hh;
    vl[e] = (short)bf_rne(x[e] - bf_f(hh));
  }
  const size_t base = (size_t)ck * 1024 + lane * 8;
  *(bf16x8*)(frag + base) = vh;
  *(bf16x8*)(frag + base + 512) = vl;
}

// decoder embedding fp32 [32000][512] -> per-row bf16 hi/lo: debf[r][0..511]=hi, [512..1023]=lo
__global__ __launch_bounds__(256)
void demb2bf(const float* __restrict__ demb, short* __restrict__ debf)
{
  const int i = blockIdx.x * 256 + threadIdx.x;   // 2,048,000 total (32000*512/8)
  if (i >= 2048000) return;
  const int r = i >> 6;
  const int k0 = (i & 63) * 8;
  const float* src = demb + (size_t)r * 512 + k0;
  const float4 v0 = *(const float4*)src;
  const float4 v1 = *(const float4*)(src + 4);
  const float x[8] = {v0.x, v0.y, v0.z, v0.w, v1.x, v1.y, v1.z, v1.w};
  bf16x8 vh, vl;
#pragma unroll
  for (int e = 0; e < 8; ++e) {
    const unsigned short h = bf_rne(x[e]);
    vh[e] = (short)h;
    vl[e] = (short)bf_rne(x[e] - bf_f(h));
  }
  *(bf16x8*)(debf + (size_t)r * 1024 + k0) = vh;
  *(bf16x8*)(debf + (size_t)r * 1024 + 512 + k0) = vl;
}

#define NBLK_CLF 500

// ---------------- decoder gates GEMM + fused LSTM update (v3: k-split, 16 waves/CU) ------
// 32 blocks x 1024 thr (16 waves). Block owns j-columns [j0, j0+16) for ALL 4 gates.
// Wave w: gate g=w&3, m-half mh=(w>>2)&1, k-half kh=w>>3.
//   kh=0: K 0..511  (pre-converted debf rows, gathered by ys)
//   kh=1: K 512..1023 (hfin fragments)
// Partials summed through gl[kh] in LDS (fp32 reassociation only).
__global__ __launch_bounds__(1024)
void dec_gates(const short* __restrict__ debf,
               const short* __restrict__ gfrag,
               const unsigned long long* __restrict__ cand, int step,
               const float* __restrict__ db,
               const short* __restrict__ hfin, short* __restrict__ hfout,
               float* __restrict__ cbuf)
{
  __shared__ int ys[64];
  __shared__ unsigned long long red[16 * 64];
  __shared__ float gl[2][4][64][16];   // [kh][g][b][jl]

  const int tid = threadIdx.x;
  const int lane = tid & 63, wv = tid >> 6;      // wv 0..15
  const int g = wv & 3, mh = (wv >> 2) & 1, kh = wv >> 3;
  const int j0 = blockIdx.x * 16;
  const int ntile = g * 32 + blockIdx.x;
  const int lrow = lane & 15, lq = lane >> 4;

  if (step == 0) {
    if (tid < 64) ys[tid] = 1;  // START_IDX
  } else {
    const int b = tid & 63, slot = tid >> 6;     // 16 slots
    unsigned long long mv = 0;
    for (int i2 = slot; i2 < NBLK_CLF; i2 += 16) {
      const unsigned long long v = cand[(size_t)i2 * 64 + b];
      mv = v > mv ? v : mv;
    }
    red[slot * 64 + b] = mv;
    __syncthreads();
    if (tid < 64) {
      unsigned long long m = red[tid];
#pragma unroll
      for (int s2 = 1; s2 < 16; ++s2) {
        const unsigned long long v = red[s2 * 64 + tid];
        m = v > m ? v : m;
      }
      ys[tid] = (int)(0xFFFFFFFFu - (unsigned)(m & 0xFFFFFFFFull));
    }
  }
  __syncthreads();

  f32x4 acc[2];
#pragma unroll
  for (int mtl = 0; mtl < 2; ++mtl) acc[mtl] = (f32x4){0.f, 0.f, 0.f, 0.f};

  if (kh == 0) {
    for (int kc = 0; kc < 16; ++kc) {
      const short* wb = gfrag + ((size_t)(ntile * 32 + kc)) * 1024 + lane * 8;
      const bf16x8 bhi = *(const bf16x8*)wb;
      const bf16x8 blo = *(const bf16x8*)(wb + 512);
      const int k0 = kc * 32 + lq * 8;
#pragma unroll
      for (int mtl = 0; mtl < 2; ++mtl) {
        const int b = (mh * 2 + mtl) * 16 + lrow;
        const short* ap = debf + (size_t)ys[b] * 1024 + k0;
        const bf16x8 ahi = *(const bf16x8*)ap;
        const bf16x8 alo = *(const bf16x8*)(ap + 512);
        acc[mtl] = __builtin_amdgcn_mfma_f32_16x16x32_bf16(ahi, bhi, acc[mtl], 0, 0, 0);
        acc[mtl] = __builtin_amdgcn_mfma_f32_16x16x32_bf16(alo, bhi, acc[mtl], 0, 0, 0);
        acc[mtl] = __builtin_amdgcn_mfma_f32_16x16x32_bf16(ahi, blo, acc[mtl], 0, 0, 0);
      }
    }
  } else {
    for (int kc = 16; kc < 32; ++kc) {
      const short* wb = gfrag + ((size_t)(ntile * 32 + kc)) * 1024 + lane * 8;
      const bf16x8 bhi = *(const bf16x8*)wb;
      const bf16x8 blo = *(const bf16x8*)(wb + 512);
#pragma unroll
      for (int mtl = 0; mtl < 2; ++mtl) {
        const int mt = mh * 2 + mtl;
        const short* ab = hfin + ((size_t)(mt * 16 + (kc - 16))) * 1024 + lane * 8;
        const bf16x8 ahi = *(const bf16x8*)ab;
        const bf16x8 alo = *(const bf16x8*)(ab + 512);
        acc[mtl] = __builtin_amdgcn_mfma_f32_16x16x32_bf16(ahi, bhi, acc[mtl], 0, 0, 0);
        acc[mtl] = __builtin_amdgcn_mfma_f32_16x16x32_bf16(alo, bhi, acc[mtl], 0, 0, 0);
        acc[mtl] = __builtin_amdgcn_mfma_f32_16x16x32_bf16(ahi, blo, acc[mtl], 0, 0, 0);
      }
    }
  }

  // C/D layout: row m = (lane>>4)*4 + reg, col n = lane&15
#pragma unroll
  for (int mtl = 0; mtl < 2; ++mtl)
#pragma unroll
    for (int r = 0; r < 4; ++r) {
      const int b = (mh * 2 + mtl) * 16 + lq * 4 + r;
      gl[kh][g][b][lrow] = acc[mtl][r];
    }
  __syncthreads();

  {
    const int b = tid >> 4, jl = tid & 15;   // 1024 threads = 64b x 16j, single pass
    const int j = j0 + jl;
    const float gi = gl[0][0][b][jl] + gl[1][0][b][jl] + db[j];
    const float gf = gl[0][1][b][jl] + gl[1][1][b][jl] + db[512 + j];
    const float gg = gl[0][2][b][jl] + gl[1][2][b][jl] + db[1024 + j];
    const float go = gl[0][3][b][jl] + gl[1][3][b][jl] + db[1536 + j];
    const size_t off = (size_t)b * 512 + j;
    const float cn = sigf(gf) * cbuf[off] + sigf(gi) * tanhf(gg);
    cbuf[off] = cn;
    const float hn = sigf(go) * tanhf(cn);
    const unsigned short hh = bf_rne(hn);
    const unsigned short hl2 = bf_rne(hn - bf_f(hh));
    // 16x16 fragment (next step's gates A + classifier A)
    const int mt = b >> 4;
    const int kc = j >> 5;
    const size_t base = ((size_t)(mt * 16 + kc)) * 1024 + ((((j & 31) >> 3) * 16) + (b & 15)) * 8 + (j & 7);
    hfout[base] = (short)hh;
    hfout[base + 512] = (short)hl2;
  }
}

// ---------------- classifier: MFMA hi/lo, logits + per-block argmax (R3 form, proven) ----
// 500 blocks x 256 thr (4 waves). Wave ntile = blk*4 + wv (16 v-cols), 4 m-tiles, K=512.
template<int DIRECT>
__global__ __launch_bounds__(256)
void dec_clf(const short* __restrict__ hfrag, const short* __restrict__ wfrag,
             const float* __restrict__ clfb,
             float* __restrict__ dst, int tcol,
             unsigned long long* __restrict__ cand_out)
{
  __shared__ unsigned long long cl[4][64];
  const int tid = threadIdx.x;
  const int lane = tid & 63, wv = tid >> 6;
  const int ntile = blockIdx.x * 4 + wv;
  const int lrow = lane & 15, lq = lane >> 4;

  f32x4 acc[4];
#pragma unroll
  for (int mt = 0; mt < 4; ++mt) acc[mt] = (f32x4){0.f, 0.f, 0.f, 0.f};

#pragma unroll 2
  for (int kc = 0; kc < 16; ++kc) {
    const short* wb = wfrag + ((size_t)(ntile * 16 + kc)) * 1024 + lane * 8;
    const bf16x8 bhi = *(const bf16x8*)wb;
    const bf16x8 blo = *(const bf16x8*)(wb + 512);
#pragma unroll
    for (int mt = 0; mt < 4; ++mt) {
      const short* ab = hfrag + ((size_t)(mt * 16 + kc)) * 1024 + lane * 8;
      const bf16x8 ahi = *(const bf16x8*)ab;
      const bf16x8 alo = *(const bf16x8*)(ab + 512);
      acc[mt] = __builtin_amdgcn_mfma_f32_16x16x32_bf16(ahi, bhi, acc[mt], 0, 0, 0);
      acc[mt] = __builtin_amdgcn_mfma_f32_16x16x32_bf16(alo, bhi, acc[mt], 0, 0, 0);
      acc[mt] = __builtin_amdgcn_mfma_f32_16x16x32_bf16(ahi, blo, acc[mt], 0, 0, 0);
    }
  }

  const int v = ntile * 16 + lrow;
  const float bias = clfb[v];
#pragma unroll
  for (int mt = 0; mt < 4; ++mt) {
#pragma unroll
    for (int r = 0; r < 4; ++r) {
      const float val = acc[mt][r] + bias;
      const int b = mt * 16 + lq * 4 + r;
      if (DIRECT) __builtin_nontemporal_store(val, dst + ((size_t)b * 32000 + v) * 63 + tcol);
      else        __builtin_nontemporal_store(val, dst + (size_t)b * 32000 + v);
      unsigned u = __float_as_uint(val);
      u ^= (u & 0x80000000u) ? 0xFFFFFFFFu : 0x80000000u;
      unsigned long long p = ((unsigned long long)u << 32) |
                             (unsigned long long)(0xFFFFFFFFu - (unsigned)v);
#pragma unroll
      for (int m2 = 1; m2 < 16; m2 <<= 1) {
        const unsigned long long o = __shfl_xor(p, m2);
        p = o > p ? o : p;
      }
      if (lrow == 0) cl[wv][b] = p;
    }
  }
  __syncthreads();
  if (tid < 64) {
    unsigned long long m = cl[0][tid];
    const unsigned long long v1 = cl[1][tid];
    const unsigned long long v2 = cl[2][tid];
    const unsigned long long v3 = cl[3][tid];
    m = v1 > m ? v1 : m; m = v2 > m ? v2 : m; m = v3 > m ? v3 : m;
    cand_out[(size_t)blockIdx.x * 64 + tid] = m;
  }
}

// ws logits [t=63][b=64][v=32000] -> out [b][v][t]
__global__ __launch_bounds__(256)
void transpose_out(const float* __restrict__ ls, float* __restrict__ out)
{
  __shared__ float tile[128 * 63];
  const int b = blockIdx.y;
  const int v0 = blockIdx.x * 128;
  for (int idx = threadIdx.x; idx < 128 * 63; idx += 256) {
    const int t = idx >> 7, v = idx & 127;
    tile[v * 63 + t] = ls[((size_t)t * 64 + b) * 32000 + v0 + v];
  }
  __syncthreads();
  float4* o4 = (float4*)(out + ((size_t)b * 32000 + v0) * 63);
  const float4* t4 = (const float4*)tile;
  for (int i = threadIdx.x; i < (128 * 63) / 4; i += 256) o4[i] = t4[i];
}

extern "C" void kernel_launch(void* const* d_in, const int* in_sizes, int n_in,
                              void* d_out, int out_size, void* d_ws, size_t ws_size,
                              hipStream_t stream)
{
  const int*   x       = (const int*)d_in[0];
  const float* enc_emb = (const float*)d_in[1];
  const float* ewih_f  = (const float*)d_in[2];
  const float* ewhh_f  = (const float*)d_in[3];
  const float* eb_f    = (const float*)d_in[4];
  const float* ewih_b  = (const float*)d_in[5];
  const float* ewhh_b  = (const float*)d_in[6];
  const float* eb_b    = (const float*)d_in[7];
  const float* demb    = (const float*)d_in[8];
  const float* dwih    = (const float*)d_in[9];
  const float* dwhh    = (const float*)d_in[10];
  const float* db      = (const float*)d_in[11];
  const float* clfw    = (const float*)d_in[12];
  const float* clfb    = (const float*)d_in[13];
  float* out = (float*)d_out;
  float* ws  = (float*)d_ws;

  // ws layout (floats)
  float* xwf = ws;                        // 4,194,304
  float* xwb = xwf + 4194304;             // 4,194,304
  float* h0  = xwb + 4194304;             // 32768
  float* h1  = h0 + 32768;                // 32768 (unused, layout kept)
  float* cbf = h1 + 32768;                // 32768
  unsigned long long* cand = (unsigned long long*)(cbf + 32768);  // 32000 u64 = 64000 f
  short* wfrag  = (short*)(cbf + 32768 + 64000);      // 32,768,000 shorts = 16,384,000 f
  short* gfrag  = wfrag + 32768000;                   // 4,194,304 shorts = 2,097,152 f
  short* hfragA = gfrag + 4194304;                    // 65,536 shorts = 32768 f
  short* hfragB = hfragA + 65536;                     // 65,536 shorts = 32768 f
  short* debf   = hfragB + 65536;                     // 32,768,000 shorts = 16,384,000 f
  short* ehfF   = debf + 32768000;                    // 524,288 shorts = 262,144 f
  short* ehfB   = ehfF + 524288;                      // 524,288 shorts = 262,144 f
  float* ls = (float*)(ehfB + 524288);                // 129,024,000 f
  const size_t need_f = 4194304ull * 2 + 32768ull * 3 + 64000ull
                      + 16384000ull + 2097152ull + 32768ull * 2
                      + 16384000ull + 262144ull * 2 + 129024000ull;
  const bool wspath = ws_size >= need_f * sizeof(float);

  // one-time (per launch) weight->fragment conversions
  wconv<<<dim3(128), dim3(256), 0, stream>>>(ewhh_f, ewhh_f, 256, 256, 8, ehfF, 32768);
  wconv<<<dim3(128), dim3(256), 0, stream>>>(ewhh_b, ewhh_b, 256, 256, 8, ehfB, 32768);
  wconv<<<dim3(8000), dim3(256), 0, stream>>>(clfw, clfw, 512, 512, 16, wfrag, 2048000);
  wconv<<<dim3(1024), dim3(256), 0, stream>>>(dwih, dwhh, 512, 512, 32, gfrag, 262144);
  demb2bf<<<dim3(8000), dim3(256), 0, stream>>>(demb, debf);

  // Encoder input projections for all T: [4096,512] x [512,1024]
  dim3 gx(16, 64, 1);
  gemm_k<AM_ENC, 0, CM_PLAIN, 0><<<gx, 256, 0, stream>>>(
      nullptr, 0, enc_emb, x, nullptr, nullptr, 0, 0,
      ewih_f, nullptr, 512, eb_f, xwf, 1024, 0, 512, nullptr, nullptr, 0);
  gemm_k<AM_ENC, 0, CM_PLAIN, 0><<<gx, 256, 0, stream>>>(
      nullptr, 0, enc_emb, x, nullptr, nullptr, 0, 0,
      ewih_b, nullptr, 512, eb_b, xwb, 1024, 0, 512, nullptr, nullptr, 0);

  // Encoder recurrence: single fused kernel (both directions, all 64 steps)
  enc_fused<<<dim3(2), dim3(512), 0, stream>>>(xwf, xwb, ehfF, ehfB, h0, cbf);

  // final h in h0 -> fragment form
  h2frag<<<dim3(16), dim3(256), 0, stream>>>(h0, hfragA);

  // Decoder: 63 greedy steps, 2 kernels/step
  for (int t = 0; t < 63; ++t) {
    const short* hin = (t & 1) ? hfragB : hfragA;
    short* hout      = (t & 1) ? hfragA : hfragB;
    dec_gates<<<dim3(32), dim3(1024), 0, stream>>>(debf, gfrag, cand, t, db, hin, hout, cbf);
    if (wspath) {
      dec_clf<0><<<dim3(NBLK_CLF), dim3(256), 0, stream>>>(
          hout, wfrag, clfb, ls + (size_t)t * 2048000, t, cand);
    } else {
      dec_clf<1><<<dim3(NBLK_CLF), dim3(256), 0, stream>>>(
          hout, wfrag, clfb, out, t, cand);
    }
  }

  if (wspath) transpose_out<<<dim3(250, 64), 256, 0, stream>>>(ls, out);
}

// Round 7
// 3922.462 us; speedup vs baseline: 1.5816x; 1.5816x over previous
//
#include <hip/hip_runtime.h>
#include <math.h>

#define AM_PLAIN 0
#define AM_ENC   1
#define CM_PLAIN 0

typedef short bf16x8 __attribute__((ext_vector_type(8)));
typedef float f32x4 __attribute__((ext_vector_type(4)));

__device__ __forceinline__ float sigf(float x) { return 1.0f / (1.0f + expf(-x)); }

__device__ __forceinline__ unsigned short bf_rne(float f) {
  unsigned u = __float_as_uint(f);
  u += 0x7FFFu + ((u >> 16) & 1u);
  return (unsigned short)(u >> 16);
}
__device__ __forceinline__ float bf_f(unsigned short h) {
  return __uint_as_float(((unsigned)h) << 16);
}

// ---------------- fp32 VALU GEMM (kept for encoder input projection) ----------------
template<int AMODE, int BTWO, int CMODE, int CDIR>
__global__ __launch_bounds__(256)
void gemm_k(const float* __restrict__ Ap, int lda,
            const float* __restrict__ emb,
            const int* __restrict__ xidx,
            const float* __restrict__ hbuf,
            const unsigned long long* __restrict__ cand_in, int nblk_cand, int step,
            const float* __restrict__ B0, const float* __restrict__ B1, int ldb,
            const float* __restrict__ bias,
            float* __restrict__ Cp, int ldc, long long zstride, int kper,
            unsigned long long* __restrict__ cand_out,
            float* __restrict__ dout, int tcol)
{
  __shared__ float As[32][68];
  __shared__ float Bs[32][68];
  __shared__ int ys[(AMODE == AM_PLAIN) ? 1 : 64];

  const int tid = threadIdx.x;
  const int tx = tid & 15, my = tid >> 4;
  const int n0 = tx * 4, m0 = my * 4;
  const int nbase = blockIdx.x * 64, mbase = blockIdx.y * 64;
  const int bz = blockIdx.z;

  if (AMODE == AM_ENC) {
    if (tid < 64) ys[tid] = xidx[tid * 64 + blockIdx.y];
  }
  if (AMODE != AM_PLAIN) __syncthreads();

  float acc[4][4];
#pragma unroll
  for (int i = 0; i < 4; ++i)
#pragma unroll
    for (int j = 0; j < 4; ++j) acc[i][j] = 0.0f;

  const int kbeg = bz * kper;
  const int lrow = tid >> 3, lk = (tid & 7) * 4;

  for (int kc = 0; kc < kper; kc += 32) {
    const int kg = kbeg + kc;
#pragma unroll
    for (int rr = 0; rr < 64; rr += 32) {
      const int row = lrow + rr;
      const float* ap;
      if (AMODE == AM_PLAIN) {
        ap = Ap + (size_t)(mbase + row) * lda + kg + lk;
      } else {
        ap = emb + (size_t)ys[row] * 512 + kg + lk;
      }
      const float4 v = *(const float4*)ap;
      As[lk + 0][row] = v.x; As[lk + 1][row] = v.y;
      As[lk + 2][row] = v.z; As[lk + 3][row] = v.w;

      const int n = nbase + row;
      const float* bp = B0 + (size_t)n * ldb + kg + lk;
      const float4 w = *(const float4*)bp;
      Bs[lk + 0][row] = w.x; Bs[lk + 1][row] = w.y;
      Bs[lk + 2][row] = w.z; Bs[lk + 3][row] = w.w;
    }
    __syncthreads();
#pragma unroll
    for (int k = 0; k < 32; ++k) {
      const float4 a = *(const float4*)&As[k][m0];
      const float4 b = *(const float4*)&Bs[k][n0];
      acc[0][0] += a.x * b.x; acc[0][1] += a.x * b.y; acc[0][2] += a.x * b.z; acc[0][3] += a.x * b.w;
      acc[1][0] += a.y * b.x; acc[1][1] += a.y * b.y; acc[1][2] += a.y * b.z; acc[1][3] += a.y * b.w;
      acc[2][0] += a.z * b.x; acc[2][1] += a.z * b.y; acc[2][2] += a.z * b.z; acc[2][3] += a.z * b.w;
      acc[3][0] += a.w * b.x; acc[3][1] += a.w * b.y; acc[3][2] += a.w * b.z; acc[3][3] += a.w * b.w;
    }
    __syncthreads();
  }

#pragma unroll
  for (int i = 0; i < 4; ++i) {
    const int m = mbase + m0 + i;
#pragma unroll
    for (int j = 0; j < 4; ++j) {
      const int n = nbase + n0 + j;
      float v = acc[i][j];
      if (bias) v += bias[n];
      Cp[bz * zstride + (size_t)m * ldc + n] = v;
    }
  }
}

// ---------------- encoder step v3: MFMA + k-split, 32 blocks x 1024 thr ----------------
// Block b: dir d = b>>4, j-slab jb = b&15 (16 cols of the 256 dir-local h dims).
// Wave w: gate g=w&3, m-half mh=(w>>2)&1, k-half kh=w>>3 (K=256 -> 2x128 = 4 kc each).
// A: h bf16 hi/lo fragments in global (ping-pong, KC=8, 4 mt per dir).
// B: Whh fragments (ehfF/ehfB). Partials summed via gl[kh] in LDS.
// Epilogue: 1024 thr, one (b,j) each: gates + x-projection (incl bias) -> LSTM update;
// c in cbuf (global), new h written as fragments for next step; fp32 h at s==63.
__global__ __launch_bounds__(1024)
void enc_mstep(const float* __restrict__ xwf, const float* __restrict__ xwb,
               const short* __restrict__ whhfF, const short* __restrict__ whhfB,
               const short* __restrict__ hin, short* __restrict__ hout,
               float* __restrict__ cbuf, float* __restrict__ hfinal, int s)
{
  __shared__ float gl[2][4][64][16];   // [kh][g][b][jl] = 32 KB

  const int blk = blockIdx.x;
  const int d = blk >> 4;
  const int jb = blk & 15;
  const int j0 = jb * 16;
  const float* xw = d ? xwb : xwf;
  const short* wf = d ? whhfB : whhfF;
  const short* hi_ = hin + d * 32768;
  short* ho_ = hout + d * 32768;
  const int t = d ? (63 - s) : s;

  const int tid = threadIdx.x;
  const int lane = tid & 63, wv = tid >> 6;    // 16 waves
  const int g = wv & 3, mh = (wv >> 2) & 1, kh = wv >> 3;
  const int lrow = lane & 15, lq = lane >> 4;
  const int ntile = g * 16 + jb;

  f32x4 acc[2];
#pragma unroll
  for (int mtl = 0; mtl < 2; ++mtl) acc[mtl] = (f32x4){0.f, 0.f, 0.f, 0.f};

#pragma unroll
  for (int kk = 0; kk < 4; ++kk) {
    const int kc = kh * 4 + kk;
    const short* wb = wf + ((size_t)(ntile * 8 + kc)) * 1024 + lane * 8;
    const bf16x8 bhi = *(const bf16x8*)wb;
    const bf16x8 blo = *(const bf16x8*)(wb + 512);
#pragma unroll
    for (int mtl = 0; mtl < 2; ++mtl) {
      const int mt = mh * 2 + mtl;
      const short* ab = hi_ + ((size_t)(mt * 8 + kc)) * 1024 + lane * 8;
      const bf16x8 ahi = *(const bf16x8*)ab;
      const bf16x8 alo = *(const bf16x8*)(ab + 512);
      acc[mtl] = __builtin_amdgcn_mfma_f32_16x16x32_bf16(ahi, bhi, acc[mtl], 0, 0, 0);
      acc[mtl] = __builtin_amdgcn_mfma_f32_16x16x32_bf16(alo, bhi, acc[mtl], 0, 0, 0);
      acc[mtl] = __builtin_amdgcn_mfma_f32_16x16x32_bf16(ahi, blo, acc[mtl], 0, 0, 0);
    }
  }

  // C/D layout: row m = (lane>>4)*4 + reg, col n = lane&15
#pragma unroll
  for (int mtl = 0; mtl < 2; ++mtl)
#pragma unroll
    for (int r = 0; r < 4; ++r) {
      const int b = (mh * 2 + mtl) * 16 + lq * 4 + r;
      gl[kh][g][b][lrow] = acc[mtl][r];
    }
  __syncthreads();

  {
    const int b = tid >> 4, jl = tid & 15;   // 64b x 16j, single pass
    const int j = j0 + jl;                   // dir-local col in [0,256)
    const float* xrow = xw + ((size_t)(t * 64 + b)) * 1024;
    const float gi = gl[0][0][b][jl] + gl[1][0][b][jl] + xrow[0 * 256 + j];
    const float gf = gl[0][1][b][jl] + gl[1][1][b][jl] + xrow[1 * 256 + j];
    const float gg = gl[0][2][b][jl] + gl[1][2][b][jl] + xrow[2 * 256 + j];
    const float go = gl[0][3][b][jl] + gl[1][3][b][jl] + xrow[3 * 256 + j];
    const size_t off = (size_t)b * 512 + d * 256 + j;
    const float cn = sigf(gf) * cbuf[off] + sigf(gi) * tanhf(gg);
    cbuf[off] = cn;
    const float hn = sigf(go) * tanhf(cn);
    const unsigned short hh = bf_rne(hn);
    const unsigned short ll = bf_rne(hn - bf_f(hh));
    const int mt = b >> 4;
    const int base = ((mt * 8 + (j >> 5)) * 2) * 512 + (((j >> 3) & 3) * 16 + (b & 15)) * 8 + (j & 7);
    ho_[base] = (short)hh;
    ho_[base + 512] = (short)ll;
    if (s == 63) hfinal[off] = hn;
  }
}

// zero c-buffer and the initial encoder h-fragment ping buffer
__global__ void kinit2(float* __restrict__ c, int* __restrict__ he)
{
  const int i = blockIdx.x * 256 + threadIdx.x;
  if (i < 32768) { c[i] = 0.f; he[i] = 0; }
}

// ---------------- weight -> MFMA-fragment conversion (hi/lo bf16 split) ----------------
// frag[((nt*KC + kc)*2 + hl)*512 + lane*8 + e] holds W[n][k] with
// n = nt*16 + (lane&15), k = kc*32 + (lane>>4)*8 + e.  Rows split at k=split (p0|p1).
__global__ __launch_bounds__(256)
void wconv(const float* __restrict__ p0, const float* __restrict__ p1,
           int ld, int split, int KC, short* __restrict__ frag, int total)
{
  const int i = blockIdx.x * 256 + threadIdx.x;
  if (i >= total) return;
  const int lane = i & 63;
  const int ck = i >> 6;                 // nt*KC + kc
  const int kc = ck % KC;
  const int nt = ck / KC;
  const int n = nt * 16 + (lane & 15);
  const int k0 = kc * 32 + (lane >> 4) * 8;
  const float* src = (k0 < split) ? (p0 + (size_t)n * ld + k0)
                                  : (p1 + (size_t)n * ld + (k0 - split));
  const float4 v0 = *(const float4*)src;
  const float4 v1 = *(const float4*)(src + 4);
  const float x[8] = {v0.x, v0.y, v0.z, v0.w, v1.x, v1.y, v1.z, v1.w};
  bf16x8 vh, vl;
#pragma unroll
  for (int e = 0; e < 8; ++e) {
    const unsigned short h = bf_rne(x[e]);
    vh[e] = (short)h;
    vl[e] = (short)bf_rne(x[e] - bf_f(h));
  }
  const size_t base = (size_t)ck * 1024 + lane * 8;
  *(bf16x8*)(frag + base) = vh;
  *(bf16x8*)(frag + base + 512) = vl;
}

// h fp32 [64][512] -> fragment hi/lo (KC=16): frag[((mt*16+kc)*2+hl)*512 + lane*8 + e]
__global__ __launch_bounds__(256)
void h2frag(const float* __restrict__ h, short* __restrict__ frag)
{
  const int i = blockIdx.x * 256 + threadIdx.x;  // 4096 total
  const int lane = i & 63;
  const int ck = i >> 6;                          // mt*16 + kc
  const int b = (ck >> 4) * 16 + (lane & 15);
  const int k0 = (ck & 15) * 32 + (lane >> 4) * 8;
  const float* src = h + (size_t)b * 512 + k0;
  const float4 v0 = *(const float4*)src;
  const float4 v1 = *(const float4*)(src + 4);
  const float x[8] = {v0.x, v0.y, v0.z, v0.w, v1.x, v1.y, v1.z, v1.w};
  bf16x8 vh, vl;
#pragma unroll
  for (int e = 0; e < 8; ++e) {
    const unsigned short hh = bf_rne(x[e]);
    vh[e] = (short)hh;
    vl[e] = (short)bf_rne(x[e] - bf_f(hh));
  }
  const size_t base = (size_t)ck * 1024 + lane * 8;
  *(bf16x8*)(frag + base) = vh;
  *(bf16x8*)(frag + base + 512) = vl;
}

// decoder embedding fp32 [32000][512] -> per-row bf16 hi/lo: debf[r][0..511]=hi, [512..1023]=lo
__global__ __launch_bounds__(256)
void demb2bf(const float* __restrict__ demb, short* __restrict__ debf)
{
  const int i = blockIdx.x * 256 + threadIdx.x;   // 2,048,000 total (32000*512/8)
  if (i >= 2048000) return;
  const int r = i >> 6;
  const int k0 = (i & 63) * 8;
  const float* src = demb + (size_t)r * 512 + k0;
  const float4 v0 = *(const float4*)src;
  const float4 v1 = *(const float4*)(src + 4);
  const float x[8] = {v0.x, v0.y, v0.z, v0.w, v1.x, v1.y, v1.z, v1.w};
  bf16x8 vh, vl;
#pragma unroll
  for (int e = 0; e < 8; ++e) {
    const unsigned short h = bf_rne(x[e]);
    vh[e] = (short)h;
    vl[e] = (short)bf_rne(x[e] - bf_f(h));
  }
  *(bf16x8*)(debf + (size_t)r * 1024 + k0) = vh;
  *(bf16x8*)(debf + (size_t)r * 1024 + 512 + k0) = vl;
}

#define NBLK_CLF 500

// ---------------- decoder gates GEMM + fused LSTM update (v3: k-split, 16 waves/CU) ------
// 32 blocks x 1024 thr (16 waves). Block owns j-columns [j0, j0+16) for ALL 4 gates.
// Wave w: gate g=w&3, m-half mh=(w>>2)&1, k-half kh=w>>3.
//   kh=0: K 0..511  (pre-converted debf rows, gathered by ys)
//   kh=1: K 512..1023 (hfin fragments)
// Partials summed through gl[kh] in LDS (fp32 reassociation only).
__global__ __launch_bounds__(1024)
void dec_gates(const short* __restrict__ debf,
               const short* __restrict__ gfrag,
               const unsigned long long* __restrict__ cand, int step,
               const float* __restrict__ db,
               const short* __restrict__ hfin, short* __restrict__ hfout,
               float* __restrict__ cbuf)
{
  __shared__ int ys[64];
  __shared__ unsigned long long red[16 * 64];
  __shared__ float gl[2][4][64][16];   // [kh][g][b][jl]

  const int tid = threadIdx.x;
  const int lane = tid & 63, wv = tid >> 6;      // wv 0..15
  const int g = wv & 3, mh = (wv >> 2) & 1, kh = wv >> 3;
  const int j0 = blockIdx.x * 16;
  const int ntile = g * 32 + blockIdx.x;
  const int lrow = lane & 15, lq = lane >> 4;

  if (step == 0) {
    if (tid < 64) ys[tid] = 1;  // START_IDX
  } else {
    const int b = tid & 63, slot = tid >> 6;     // 16 slots
    unsigned long long mv = 0;
    for (int i2 = slot; i2 < NBLK_CLF; i2 += 16) {
      const unsigned long long v = cand[(size_t)i2 * 64 + b];
      mv = v > mv ? v : mv;
    }
    red[slot * 64 + b] = mv;
    __syncthreads();
    if (tid < 64) {
      unsigned long long m = red[tid];
#pragma unroll
      for (int s2 = 1; s2 < 16; ++s2) {
        const unsigned long long v = red[s2 * 64 + tid];
        m = v > m ? v : m;
      }
      ys[tid] = (int)(0xFFFFFFFFu - (unsigned)(m & 0xFFFFFFFFull));
    }
  }
  __syncthreads();

  f32x4 acc[2];
#pragma unroll
  for (int mtl = 0; mtl < 2; ++mtl) acc[mtl] = (f32x4){0.f, 0.f, 0.f, 0.f};

  if (kh == 0) {
    for (int kc = 0; kc < 16; ++kc) {
      const short* wb = gfrag + ((size_t)(ntile * 32 + kc)) * 1024 + lane * 8;
      const bf16x8 bhi = *(const bf16x8*)wb;
      const bf16x8 blo = *(const bf16x8*)(wb + 512);
      const int k0 = kc * 32 + lq * 8;
#pragma unroll
      for (int mtl = 0; mtl < 2; ++mtl) {
        const int b = (mh * 2 + mtl) * 16 + lrow;
        const short* ap = debf + (size_t)ys[b] * 1024 + k0;
        const bf16x8 ahi = *(const bf16x8*)ap;
        const bf16x8 alo = *(const bf16x8*)(ap + 512);
        acc[mtl] = __builtin_amdgcn_mfma_f32_16x16x32_bf16(ahi, bhi, acc[mtl], 0, 0, 0);
        acc[mtl] = __builtin_amdgcn_mfma_f32_16x16x32_bf16(alo, bhi, acc[mtl], 0, 0, 0);
        acc[mtl] = __builtin_amdgcn_mfma_f32_16x16x32_bf16(ahi, blo, acc[mtl], 0, 0, 0);
      }
    }
  } else {
    for (int kc = 16; kc < 32; ++kc) {
      const short* wb = gfrag + ((size_t)(ntile * 32 + kc)) * 1024 + lane * 8;
      const bf16x8 bhi = *(const bf16x8*)wb;
      const bf16x8 blo = *(const bf16x8*)(wb + 512);
#pragma unroll
      for (int mtl = 0; mtl < 2; ++mtl) {
        const int mt = mh * 2 + mtl;
        const short* ab = hfin + ((size_t)(mt * 16 + (kc - 16))) * 1024 + lane * 8;
        const bf16x8 ahi = *(const bf16x8*)ab;
        const bf16x8 alo = *(const bf16x8*)(ab + 512);
        acc[mtl] = __builtin_amdgcn_mfma_f32_16x16x32_bf16(ahi, bhi, acc[mtl], 0, 0, 0);
        acc[mtl] = __builtin_amdgcn_mfma_f32_16x16x32_bf16(alo, bhi, acc[mtl], 0, 0, 0);
        acc[mtl] = __builtin_amdgcn_mfma_f32_16x16x32_bf16(ahi, blo, acc[mtl], 0, 0, 0);
      }
    }
  }

  // C/D layout: row m = (lane>>4)*4 + reg, col n = lane&15
#pragma unroll
  for (int mtl = 0; mtl < 2; ++mtl)
#pragma unroll
    for (int r = 0; r < 4; ++r) {
      const int b = (mh * 2 + mtl) * 16 + lq * 4 + r;
      gl[kh][g][b][lrow] = acc[mtl][r];
    }
  __syncthreads();

  {
    const int b = tid >> 4, jl = tid & 15;   // 1024 threads = 64b x 16j, single pass
    const int j = j0 + jl;
    const float gi = gl[0][0][b][jl] + gl[1][0][b][jl] + db[j];
    const float gf = gl[0][1][b][jl] + gl[1][1][b][jl] + db[512 + j];
    const float gg = gl[0][2][b][jl] + gl[1][2][b][jl] + db[1024 + j];
    const float go = gl[0][3][b][jl] + gl[1][3][b][jl] + db[1536 + j];
    const size_t off = (size_t)b * 512 + j;
    const float cn = sigf(gf) * cbuf[off] + sigf(gi) * tanhf(gg);
    cbuf[off] = cn;
    const float hn = sigf(go) * tanhf(cn);
    const unsigned short hh = bf_rne(hn);
    const unsigned short hl2 = bf_rne(hn - bf_f(hh));
    // 16x16 fragment (next step's gates A + classifier A)
    const int mt = b >> 4;
    const int kc = j >> 5;
    const size_t base = ((size_t)(mt * 16 + kc)) * 1024 + ((((j & 31) >> 3) * 16) + (b & 15)) * 8 + (j & 7);
    hfout[base] = (short)hh;
    hfout[base + 512] = (short)hl2;
  }
}

// ---------------- classifier: MFMA hi/lo, logits + per-block argmax (R3 form, proven) ----
// 500 blocks x 256 thr (4 waves). Wave ntile = blk*4 + wv (16 v-cols), 4 m-tiles, K=512.
template<int DIRECT>
__global__ __launch_bounds__(256)
void dec_clf(const short* __restrict__ hfrag, const short* __restrict__ wfrag,
             const float* __restrict__ clfb,
             float* __restrict__ dst, int tcol,
             unsigned long long* __restrict__ cand_out)
{
  __shared__ unsigned long long cl[4][64];
  const int tid = threadIdx.x;
  const int lane = tid & 63, wv = tid >> 6;
  const int ntile = blockIdx.x * 4 + wv;
  const int lrow = lane & 15, lq = lane >> 4;

  f32x4 acc[4];
#pragma unroll
  for (int mt = 0; mt < 4; ++mt) acc[mt] = (f32x4){0.f, 0.f, 0.f, 0.f};

#pragma unroll 2
  for (int kc = 0; kc < 16; ++kc) {
    const short* wb = wfrag + ((size_t)(ntile * 16 + kc)) * 1024 + lane * 8;
    const bf16x8 bhi = *(const bf16x8*)wb;
    const bf16x8 blo = *(const bf16x8*)(wb + 512);
#pragma unroll
    for (int mt = 0; mt < 4; ++mt) {
      const short* ab = hfrag + ((size_t)(mt * 16 + kc)) * 1024 + lane * 8;
      const bf16x8 ahi = *(const bf16x8*)ab;
      const bf16x8 alo = *(const bf16x8*)(ab + 512);
      acc[mt] = __builtin_amdgcn_mfma_f32_16x16x32_bf16(ahi, bhi, acc[mt], 0, 0, 0);
      acc[mt] = __builtin_amdgcn_mfma_f32_16x16x32_bf16(alo, bhi, acc[mt], 0, 0, 0);
      acc[mt] = __builtin_amdgcn_mfma_f32_16x16x32_bf16(ahi, blo, acc[mt], 0, 0, 0);
    }
  }

  const int v = ntile * 16 + lrow;
  const float bias = clfb[v];
#pragma unroll
  for (int mt = 0; mt < 4; ++mt) {
#pragma unroll
    for (int r = 0; r < 4; ++r) {
      const float val = acc[mt][r] + bias;
      const int b = mt * 16 + lq * 4 + r;
      if (DIRECT) __builtin_nontemporal_store(val, dst + ((size_t)b * 32000 + v) * 63 + tcol);
      else        __builtin_nontemporal_store(val, dst + (size_t)b * 32000 + v);
      unsigned u = __float_as_uint(val);
      u ^= (u & 0x80000000u) ? 0xFFFFFFFFu : 0x80000000u;
      unsigned long long p = ((unsigned long long)u << 32) |
                             (unsigned long long)(0xFFFFFFFFu - (unsigned)v);
#pragma unroll
      for (int m2 = 1; m2 < 16; m2 <<= 1) {
        const unsigned long long o = __shfl_xor(p, m2);
        p = o > p ? o : p;
      }
      if (lrow == 0) cl[wv][b] = p;
    }
  }
  __syncthreads();
  if (tid < 64) {
    unsigned long long m = cl[0][tid];
    const unsigned long long v1 = cl[1][tid];
    const unsigned long long v2 = cl[2][tid];
    const unsigned long long v3 = cl[3][tid];
    m = v1 > m ? v1 : m; m = v2 > m ? v2 : m; m = v3 > m ? v3 : m;
    cand_out[(size_t)blockIdx.x * 64 + tid] = m;
  }
}

// ws logits [t=63][b=64][v=32000] -> out [b][v][t]
__global__ __launch_bounds__(256)
void transpose_out(const float* __restrict__ ls, float* __restrict__ out)
{
  __shared__ float tile[128 * 63];
  const int b = blockIdx.y;
  const int v0 = blockIdx.x * 128;
  for (int idx = threadIdx.x; idx < 128 * 63; idx += 256) {
    const int t = idx >> 7, v = idx & 127;
    tile[v * 63 + t] = ls[((size_t)t * 64 + b) * 32000 + v0 + v];
  }
  __syncthreads();
  float4* o4 = (float4*)(out + ((size_t)b * 32000 + v0) * 63);
  const float4* t4 = (const float4*)tile;
  for (int i = threadIdx.x; i < (128 * 63) / 4; i += 256) o4[i] = t4[i];
}

extern "C" void kernel_launch(void* const* d_in, const int* in_sizes, int n_in,
                              void* d_out, int out_size, void* d_ws, size_t ws_size,
                              hipStream_t stream)
{
  const int*   x       = (const int*)d_in[0];
  const float* enc_emb = (const float*)d_in[1];
  const float* ewih_f  = (const float*)d_in[2];
  const float* ewhh_f  = (const float*)d_in[3];
  const float* eb_f    = (const float*)d_in[4];
  const float* ewih_b  = (const float*)d_in[5];
  const float* ewhh_b  = (const float*)d_in[6];
  const float* eb_b    = (const float*)d_in[7];
  const float* demb    = (const float*)d_in[8];
  const float* dwih    = (const float*)d_in[9];
  const float* dwhh    = (const float*)d_in[10];
  const float* db      = (const float*)d_in[11];
  const float* clfw    = (const float*)d_in[12];
  const float* clfb    = (const float*)d_in[13];
  float* out = (float*)d_out;
  float* ws  = (float*)d_ws;

  // ws layout (floats)
  float* xwf = ws;                        // 4,194,304
  float* xwb = xwf + 4194304;             // 4,194,304
  float* h0  = xwb + 4194304;             // 32768
  float* h1  = h0 + 32768;                // 32768 (unused, layout kept)
  float* cbf = h1 + 32768;                // 32768
  unsigned long long* cand = (unsigned long long*)(cbf + 32768);  // 32000 u64 = 64000 f
  short* wfrag  = (short*)(cbf + 32768 + 64000);      // 32,768,000 shorts = 16,384,000 f
  short* gfrag  = wfrag + 32768000;                   // 4,194,304 shorts = 2,097,152 f
  short* hfragA = gfrag + 4194304;                    // 65,536 shorts = 32768 f
  short* hfragB = hfragA + 65536;                     // 65,536 shorts = 32768 f
  short* debf   = hfragB + 65536;                     // 32,768,000 shorts = 16,384,000 f
  short* ehfF   = debf + 32768000;                    // 524,288 shorts = 262,144 f
  short* ehfB   = ehfF + 524288;                      // 524,288 shorts = 262,144 f
  short* he0    = ehfB + 524288;                      // 65,536 shorts = 32768 f (2 dirs x 32768)
  short* he1    = he0 + 65536;                        // 65,536 shorts = 32768 f
  float* ls = (float*)(he1 + 65536);                  // 129,024,000 f
  const size_t need_f = 4194304ull * 2 + 32768ull * 3 + 64000ull
                      + 16384000ull + 2097152ull + 32768ull * 2
                      + 16384000ull + 262144ull * 2 + 32768ull * 2 + 129024000ull;
  const bool wspath = ws_size >= need_f * sizeof(float);

  // zero c-buffer and initial encoder h-fragments
  kinit2<<<dim3(128), dim3(256), 0, stream>>>(cbf, (int*)he0);

  // one-time (per launch) weight->fragment conversions
  wconv<<<dim3(128), dim3(256), 0, stream>>>(ewhh_f, ewhh_f, 256, 256, 8, ehfF, 32768);
  wconv<<<dim3(128), dim3(256), 0, stream>>>(ewhh_b, ewhh_b, 256, 256, 8, ehfB, 32768);
  wconv<<<dim3(8000), dim3(256), 0, stream>>>(clfw, clfw, 512, 512, 16, wfrag, 2048000);
  wconv<<<dim3(1024), dim3(256), 0, stream>>>(dwih, dwhh, 512, 512, 32, gfrag, 262144);
  demb2bf<<<dim3(8000), dim3(256), 0, stream>>>(demb, debf);

  // Encoder input projections for all T: [4096,512] x [512,1024]
  dim3 gx(16, 64, 1);
  gemm_k<AM_ENC, 0, CM_PLAIN, 0><<<gx, 256, 0, stream>>>(
      nullptr, 0, enc_emb, x, nullptr, nullptr, 0, 0,
      ewih_f, nullptr, 512, eb_f, xwf, 1024, 0, 512, nullptr, nullptr, 0);
  gemm_k<AM_ENC, 0, CM_PLAIN, 0><<<gx, 256, 0, stream>>>(
      nullptr, 0, enc_emb, x, nullptr, nullptr, 0, 0,
      ewih_b, nullptr, 512, eb_b, xwb, 1024, 0, 512, nullptr, nullptr, 0);

  // Encoder recurrence: 64 MFMA k-split steps (both directions per launch)
  for (int s = 0; s < 64; ++s) {
    const short* hin = (s & 1) ? he1 : he0;
    short* hout      = (s & 1) ? he0 : he1;
    enc_mstep<<<dim3(32), dim3(1024), 0, stream>>>(
        xwf, xwb, ehfF, ehfB, hin, hout, cbf, h0, s);
  }

  // final h in h0 -> fragment form
  h2frag<<<dim3(16), dim3(256), 0, stream>>>(h0, hfragA);

  // Decoder: 63 greedy steps, 2 kernels/step
  for (int t = 0; t < 63; ++t) {
    const short* hin = (t & 1) ? hfragB : hfragA;
    short* hout      = (t & 1) ? hfragA : hfragB;
    dec_gates<<<dim3(32), dim3(1024), 0, stream>>>(debf, gfrag, cand, t, db, hin, hout, cbf);
    if (wspath) {
      dec_clf<0><<<dim3(NBLK_CLF), dim3(256), 0, stream>>>(
          hout, wfrag, clfb, ls + (size_t)t * 2048000, t, cand);
    } else {
      dec_clf<1><<<dim3(NBLK_CLF), dim3(256), 0, stream>>>(
          hout, wfrag, clfb, out, t, cand);
    }
  }

  if (wspath) transpose_out<<<dim3(250, 64), 256, 0, stream>>>(ls, out);
}